// Round 6
// baseline (221.524 us; speedup 1.0000x reference)
//
#include <hip/hip_runtime.h>
#include <hip/hip_bf16.h>

#define NB 16
#define CIN 256
#define CA 32
#define CH 128
#define NN 4096
#define MM 1024

typedef __attribute__((ext_vector_type(8))) short s16x8;
typedef __attribute__((ext_vector_type(4))) float f32x4;

static __device__ __forceinline__ unsigned short f2bf(float x) {
  __hip_bfloat16 h = __float2bfloat16(x);
  return __builtin_bit_cast(unsigned short, h);
}
static __device__ __forceinline__ float bf2f(unsigned short u) {
  unsigned int v = ((unsigned int)u) << 16;
  return __builtin_bit_cast(float, v);
}

// Build wcat (192x256 bf16 = [w_theta; w_phi; w_g]) and wob (256x128 bf16).
__global__ __launch_bounds__(256) void k_wcvt(const float* __restrict__ w_theta,
                                              const float* __restrict__ w_phi,
                                              const float* __restrict__ w_g,
                                              const float* __restrict__ w_o,
                                              unsigned short* __restrict__ wcat,
                                              unsigned short* __restrict__ wob) {
  const int i = blockIdx.x * 256 + threadIdx.x;
  if (i < 8192) wcat[i] = f2bf(w_theta[i]);
  else if (i < 16384) wcat[i] = f2bf(w_phi[i - 8192]);
  else if (i < 49152) wcat[i] = f2bf(w_g[i - 16384]);
  else wob[i - 49152] = f2bf(w_o[i - 49152]);
}

// MFMA projection: conv = wcat @ x_b (192 x 4096 per batch), staged in LDS,
// then: rows 0..31 -> theta; rows 32..63 -> pool -> phi; rows 64..191 -> pool -> g.
__global__ __launch_bounds__(512) void k_proj(const float* __restrict__ x,
                                              const unsigned short* __restrict__ wcat,
                                              unsigned short* __restrict__ theta,
                                              unsigned short* __restrict__ phi,
                                              unsigned short* __restrict__ g) {
  __shared__ unsigned short ol[192][136];
  const int b = blockIdx.y;
  const int t = blockIdx.x;
  const int tid = threadIdx.x;
  const int wv = tid >> 6;
  const int l = tid & 63;
  const int grp = l >> 4, col = l & 15;
  const int n0 = t * 128 + wv * 16;
  const float* xb = x + (size_t)b * CIN * NN;
  f32x4 acc[12];
#pragma unroll
  for (int r = 0; r < 12; ++r) acc[r] = f32x4{0.f, 0.f, 0.f, 0.f};
#pragma unroll 1
  for (int kc = 0; kc < 8; ++kc) {
    const int c0 = kc * 32 + grp * 8;
    s16x8 bfrag;
#pragma unroll
    for (int j = 0; j < 8; ++j)
      bfrag[j] = (short)f2bf(xb[(size_t)(c0 + j) * NN + n0 + col]);
#pragma unroll
    for (int r = 0; r < 12; ++r) {
      const s16x8 af = *reinterpret_cast<const s16x8*>(
          wcat + (size_t)(r * 16 + col) * CIN + c0);
      acc[r] = __builtin_amdgcn_mfma_f32_16x16x32_bf16(af, bfrag, acc[r], 0, 0, 0);
    }
  }
#pragma unroll
  for (int r = 0; r < 12; ++r)
#pragma unroll
    for (int q = 0; q < 4; ++q)
      ol[r * 16 + grp * 4 + q][wv * 16 + col] = f2bf(acc[r][q]);
  __syncthreads();
  unsigned short* thb = theta + (size_t)b * NN * CA;
  for (int i = tid; i < 128 * 16; i += 512) {
    const int n = i >> 4, cp = (i & 15) << 1;
    const unsigned int v = (unsigned)ol[cp][n] | ((unsigned)ol[cp + 1][n] << 16);
    *reinterpret_cast<unsigned int*>(thb + (size_t)(t * 128 + n) * CA + cp) = v;
  }
  unsigned short* phb = phi + (size_t)b * MM * CA;
  for (int i = tid; i < 32 * 32; i += 512) {
    const int ca = i & 31, mx = i >> 5;
    const float v = fmaxf(
        fmaxf(bf2f(ol[32 + ca][2 * mx]), bf2f(ol[32 + ca][2 * mx + 1])),
        fmaxf(bf2f(ol[32 + ca][64 + 2 * mx]), bf2f(ol[32 + ca][64 + 2 * mx + 1])));
    phb[(size_t)(t * 32 + mx) * CA + ca] = f2bf(v);
  }
  unsigned short* gb = g + (size_t)b * CH * MM;
  for (int i = tid; i < 128 * 32; i += 512) {
    const int mx = i & 31, c = i >> 5;
    const float v = fmaxf(
        fmaxf(bf2f(ol[64 + c][2 * mx]), bf2f(ol[64 + c][2 * mx + 1])),
        fmaxf(bf2f(ol[64 + c][64 + 2 * mx]), bf2f(ol[64 + c][64 + 2 * mx + 1])));
    gb[(size_t)c * MM + t * 32 + mx] = f2bf(v);
  }
}

// Flash attention, split-K: a PAIR of waves shares one 16-col n-tile, each wave
// covers 512 keys in 64-key chunks (4 QK MFMA + merged softmax + 16 PV MFMA per
// chunk), then merges (m,l,O) via LDS and splits the 256-row out-projection.
__global__ __launch_bounds__(256, 6) void k_attn_out(
    const unsigned short* __restrict__ theta, const unsigned short* __restrict__ phi,
    const unsigned short* __restrict__ g, const unsigned short* __restrict__ wo,
    const float* __restrict__ x, const float* __restrict__ gammap,
    float* __restrict__ out) {
  __shared__ unsigned short pl[4][16][72];  // [wave][n(16)][m(64)+pad8]
  __shared__ unsigned short ob[2][16][136]; // [pair][n(16)][c(128)+pad8] merge buf
  __shared__ float mlb[4][2][16];           // [wave][{m,l}][n]
  const int b = blockIdx.y;
  const int tid = threadIdx.x;
  const int wv = tid >> 6;
  const int pr = wv >> 1;      // pair id (owns an n-tile)
  const int h = wv & 1;        // key-half
  const int l = tid & 63;
  const int grp = l >> 4, col = l & 15;
  const int n0 = blockIdx.x * 32 + pr * 16;
  const s16x8 qf = *reinterpret_cast<const s16x8*>(
      theta + ((size_t)b * NN + n0 + col) * CA + grp * 8);
  f32x4 oacc[8];
#pragma unroll
  for (int t = 0; t < 8; ++t) oacc[t] = f32x4{0.f, 0.f, 0.f, 0.f};
  float mrow = -INFINITY, lrow = 0.f;
  const unsigned short* phb = phi + (size_t)b * MM * CA;
  const unsigned short* gb = g + (size_t)b * CH * MM;
  const f32x4 z4 = {0.f, 0.f, 0.f, 0.f};
#pragma unroll 1
  for (int it = 0; it < 8; ++it) {
    const int mc = h * 512 + it * 64;
    const s16x8 kf0 = *reinterpret_cast<const s16x8*>(phb + (size_t)(mc + col) * CA + grp * 8);
    const s16x8 kf1 = *reinterpret_cast<const s16x8*>(phb + (size_t)(mc + 16 + col) * CA + grp * 8);
    const s16x8 kf2 = *reinterpret_cast<const s16x8*>(phb + (size_t)(mc + 32 + col) * CA + grp * 8);
    const s16x8 kf3 = *reinterpret_cast<const s16x8*>(phb + (size_t)(mc + 48 + col) * CA + grp * 8);
    f32x4 s0 = __builtin_amdgcn_mfma_f32_16x16x32_bf16(kf0, qf, z4, 0, 0, 0);
    f32x4 s1 = __builtin_amdgcn_mfma_f32_16x16x32_bf16(kf1, qf, z4, 0, 0, 0);
    f32x4 s2 = __builtin_amdgcn_mfma_f32_16x16x32_bf16(kf2, qf, z4, 0, 0, 0);
    f32x4 s3 = __builtin_amdgcn_mfma_f32_16x16x32_bf16(kf3, qf, z4, 0, 0, 0);
    float cm = -INFINITY;
#pragma unroll
    for (int r = 0; r < 4; ++r)
      cm = fmaxf(cm, fmaxf(fmaxf(s0[r], s1[r]), fmaxf(s2[r], s3[r])));
    cm = fmaxf(cm, __shfl_xor(cm, 16));
    cm = fmaxf(cm, __shfl_xor(cm, 32));
    if (!__all(cm <= mrow + 8.f)) {  // defer-max (T13)
      const float mnew = fmaxf(mrow, cm);
      const float scale = __expf(mrow - mnew);
      lrow *= scale;
#pragma unroll
      for (int t = 0; t < 8; ++t) {
#pragma unroll
        for (int r = 0; r < 4; ++r) oacc[t][r] *= scale;
      }
      mrow = mnew;
    }
    float p0[4], p1[4], p2[4], p3[4];
    float cs = 0.f;
#pragma unroll
    for (int r = 0; r < 4; ++r) {
      p0[r] = __expf(s0[r] - mrow);
      p1[r] = __expf(s1[r] - mrow);
      p2[r] = __expf(s2[r] - mrow);
      p3[r] = __expf(s3[r] - mrow);
      cs += (p0[r] + p1[r]) + (p2[r] + p3[r]);
    }
    cs += __shfl_xor(cs, 16);
    cs += __shfl_xor(cs, 32);
    lrow += cs;
    *reinterpret_cast<uint2*>(&pl[wv][col][grp * 4]) =
        make_uint2((unsigned)f2bf(p0[0]) | ((unsigned)f2bf(p0[1]) << 16),
                   (unsigned)f2bf(p0[2]) | ((unsigned)f2bf(p0[3]) << 16));
    *reinterpret_cast<uint2*>(&pl[wv][col][16 + grp * 4]) =
        make_uint2((unsigned)f2bf(p1[0]) | ((unsigned)f2bf(p1[1]) << 16),
                   (unsigned)f2bf(p1[2]) | ((unsigned)f2bf(p1[3]) << 16));
    *reinterpret_cast<uint2*>(&pl[wv][col][32 + grp * 4]) =
        make_uint2((unsigned)f2bf(p2[0]) | ((unsigned)f2bf(p2[1]) << 16),
                   (unsigned)f2bf(p2[2]) | ((unsigned)f2bf(p2[3]) << 16));
    *reinterpret_cast<uint2*>(&pl[wv][col][48 + grp * 4]) =
        make_uint2((unsigned)f2bf(p3[0]) | ((unsigned)f2bf(p3[1]) << 16),
                   (unsigned)f2bf(p3[2]) | ((unsigned)f2bf(p3[3]) << 16));
    const s16x8 pfA = *reinterpret_cast<const s16x8*>(&pl[wv][col][grp * 8]);
    const s16x8 pfB = *reinterpret_cast<const s16x8*>(&pl[wv][col][32 + grp * 8]);
#pragma unroll
    for (int t = 0; t < 8; ++t) {
      const s16x8 vfA = *reinterpret_cast<const s16x8*>(
          gb + (size_t)(t * 16 + col) * MM + mc + grp * 8);
      const s16x8 vfB = *reinterpret_cast<const s16x8*>(
          gb + (size_t)(t * 16 + col) * MM + mc + 32 + grp * 8);
      oacc[t] = __builtin_amdgcn_mfma_f32_16x16x32_bf16(vfA, pfA, oacc[t], 0, 0, 0);
      oacc[t] = __builtin_amdgcn_mfma_f32_16x16x32_bf16(vfB, pfB, oacc[t], 0, 0, 0);
    }
  }
  // ---- split-K merge across the wave pair ----
  if (grp == 0) {
    mlb[wv][0][col] = mrow;
    mlb[wv][1][col] = lrow;
  }
  __syncthreads();
  const float mo = mlb[wv ^ 1][0][col];
  const float lo = mlb[wv ^ 1][1][col];
  const float mtot = fmaxf(mrow, mo);
  const float sc_self = __expf(mrow - mtot);
  const float ltot = lrow * sc_self + lo * __expf(mo - mtot);
  if (h == 1) {  // upper-half wave stages its scaled O
#pragma unroll
    for (int t = 0; t < 8; ++t) {
      const unsigned int lov = (unsigned)f2bf(oacc[t][0] * sc_self) |
                               ((unsigned)f2bf(oacc[t][1] * sc_self) << 16);
      const unsigned int hiv = (unsigned)f2bf(oacc[t][2] * sc_self) |
                               ((unsigned)f2bf(oacc[t][3] * sc_self) << 16);
      *reinterpret_cast<uint2*>(&ob[pr][col][t * 16 + grp * 4]) = make_uint2(lov, hiv);
    }
  }
  __syncthreads();
  if (h == 0) {  // lower-half wave merges + normalizes
    const float rinv = 1.f / ltot;
#pragma unroll
    for (int t = 0; t < 8; ++t) {
      float v[4];
#pragma unroll
      for (int q = 0; q < 4; ++q)
        v[q] = (oacc[t][q] * sc_self + bf2f(ob[pr][col][t * 16 + grp * 4 + q])) * rinv;
      const unsigned int lov = (unsigned)f2bf(v[0]) | ((unsigned)f2bf(v[1]) << 16);
      const unsigned int hiv = (unsigned)f2bf(v[2]) | ((unsigned)f2bf(v[3]) << 16);
      *reinterpret_cast<uint2*>(&ob[pr][col][t * 16 + grp * 4]) = make_uint2(lov, hiv);
    }
  }
  __syncthreads();
  // ---- fused out-projection: each wave of the pair does 8 of 16 row-tiles ----
  s16x8 of[4];
#pragma unroll
  for (int ks = 0; ks < 4; ++ks)
    of[ks] = *reinterpret_cast<const s16x8*>(&ob[pr][col][ks * 32 + grp * 8]);
  const float gamma = gammap[0];
  const float* xb2 = x + (size_t)b * CIN * NN;
  float* outb = out + (size_t)b * CIN * NN;
  const int t2base = h * 8;
#pragma unroll 1
  for (int t2i = 0; t2i < 8; ++t2i) {
    const int t2 = t2base + t2i;
    f32x4 a2 = {0.f, 0.f, 0.f, 0.f};
#pragma unroll
    for (int ks = 0; ks < 4; ++ks) {
      const s16x8 wf = *reinterpret_cast<const s16x8*>(
          wo + (size_t)(t2 * 16 + col) * CH + ks * 32 + grp * 8);
      a2 = __builtin_amdgcn_mfma_f32_16x16x32_bf16(wf, of[ks], a2, 0, 0, 0);
    }
#pragma unroll
    for (int r = 0; r < 4; ++r) {
      const size_t idx = (size_t)(t2 * 16 + grp * 4 + r) * NN + n0 + col;
      outb[idx] = fmaf(gamma, a2[r], xb2[idx]);
    }
  }
}

extern "C" void kernel_launch(void* const* d_in, const int* in_sizes, int n_in,
                              void* d_out, int out_size, void* d_ws, size_t ws_size,
                              hipStream_t stream) {
  const float* x = (const float*)d_in[0];
  const float* w_theta = (const float*)d_in[1];
  const float* w_phi = (const float*)d_in[2];
  const float* w_g = (const float*)d_in[3];
  const float* w_o = (const float*)d_in[4];
  const float* gamma = (const float*)d_in[5];
  float* out = (float*)d_out;
  char* ws = (char*)d_ws;
  unsigned short* theta = (unsigned short*)(ws + 0);
  unsigned short* phi = (unsigned short*)(ws + 4194304);
  unsigned short* g = (unsigned short*)(ws + 5242880);
  unsigned short* wob = (unsigned short*)(ws + 9437184);
  unsigned short* wcat = (unsigned short*)(ws + 9502720);

  k_wcvt<<<dim3(320), 256, 0, stream>>>(w_theta, w_phi, w_g, w_o, wcat, wob);
  k_proj<<<dim3(NN / 128, NB), 512, 0, stream>>>(x, wcat, theta, phi, g);
  k_attn_out<<<dim3(NN / 32, NB), 256, 0, stream>>>(theta, phi, g, wob, x, gamma, out);
}

// Round 7
// 140.453 us; speedup vs baseline: 1.5772x; 1.5772x over previous
//
#include <hip/hip_runtime.h>
#include <hip/hip_bf16.h>

#define NB 16
#define CIN 256
#define CA 32
#define CH 128
#define NN 4096
#define MM 1024

typedef __attribute__((ext_vector_type(8))) short s16x8;
typedef __attribute__((ext_vector_type(4))) float f32x4;

static __device__ __forceinline__ unsigned short f2bf(float x) {
  __hip_bfloat16 h = __float2bfloat16(x);
  return __builtin_bit_cast(unsigned short, h);
}
static __device__ __forceinline__ float bf2f(unsigned short u) {
  unsigned int v = ((unsigned int)u) << 16;
  return __builtin_bit_cast(float, v);
}

// Build wcat (192x256 bf16 = [w_theta; w_phi; w_g]) and wo2 (fragment-packed).
// wo2 layout: element (c_out, k) at ((c_out>>4)*16 + (k>>5)*4 + ((k>>3)&3))*128
//             + (c_out&15)*8 + (k&7)  -> each MFMA A-fragment is 1KB contiguous.
__global__ __launch_bounds__(256) void k_wcvt(const float* __restrict__ w_theta,
                                              const float* __restrict__ w_phi,
                                              const float* __restrict__ w_g,
                                              const float* __restrict__ w_o,
                                              unsigned short* __restrict__ wcat,
                                              unsigned short* __restrict__ wo2) {
  const int i = blockIdx.x * 256 + threadIdx.x;
  if (i < 8192) wcat[i] = f2bf(w_theta[i]);
  else if (i < 16384) wcat[i] = f2bf(w_phi[i - 8192]);
  else if (i < 49152) wcat[i] = f2bf(w_g[i - 16384]);
  else {
    const int w = i - 49152;
    const int c_out = w >> 7, k = w & 127;
    const int dst = (((c_out >> 4) * 16) + ((k >> 5) * 4) + ((k >> 3) & 3)) * 128 +
                    ((c_out & 15) << 3) + (k & 7);
    wo2[dst] = f2bf(w_o[w]);
  }
}

// MFMA projection: conv = wcat @ x_b (192 x 4096 per batch), staged in LDS,
// then: rows 0..31 -> theta; rows 32..63 -> pool -> phi; rows 64..191 -> pool -> g2.
// g2 layout: element (c, m) at ((m>>5)*8 + (c>>4))*512 + ((m>>3)&3)*128
//            + (c&15)*8 + (m&7)  -> V^T MFMA A-fragments are 1KB contiguous.
__global__ __launch_bounds__(512) void k_proj(const float* __restrict__ x,
                                              const unsigned short* __restrict__ wcat,
                                              unsigned short* __restrict__ theta,
                                              unsigned short* __restrict__ phi,
                                              unsigned short* __restrict__ g2) {
  __shared__ unsigned short ol[192][136];
  const int b = blockIdx.y;
  const int t = blockIdx.x;
  const int tid = threadIdx.x;
  const int wv = tid >> 6;
  const int l = tid & 63;
  const int grp = l >> 4, col = l & 15;
  const int n0 = t * 128 + wv * 16;
  const float* xb = x + (size_t)b * CIN * NN;
  f32x4 acc[12];
#pragma unroll
  for (int r = 0; r < 12; ++r) acc[r] = f32x4{0.f, 0.f, 0.f, 0.f};
#pragma unroll 1
  for (int kc = 0; kc < 8; ++kc) {
    const int c0 = kc * 32 + grp * 8;
    s16x8 bfrag;
#pragma unroll
    for (int j = 0; j < 8; ++j)
      bfrag[j] = (short)f2bf(xb[(size_t)(c0 + j) * NN + n0 + col]);
#pragma unroll
    for (int r = 0; r < 12; ++r) {
      const s16x8 af = *reinterpret_cast<const s16x8*>(
          wcat + (size_t)(r * 16 + col) * CIN + c0);
      acc[r] = __builtin_amdgcn_mfma_f32_16x16x32_bf16(af, bfrag, acc[r], 0, 0, 0);
    }
  }
#pragma unroll
  for (int r = 0; r < 12; ++r)
#pragma unroll
    for (int q = 0; q < 4; ++q)
      ol[r * 16 + grp * 4 + q][wv * 16 + col] = f2bf(acc[r][q]);
  __syncthreads();
  unsigned short* thb = theta + (size_t)b * NN * CA;
  for (int i = tid; i < 128 * 16; i += 512) {
    const int n = i >> 4, cp = (i & 15) << 1;
    const unsigned int v = (unsigned)ol[cp][n] | ((unsigned)ol[cp + 1][n] << 16);
    *reinterpret_cast<unsigned int*>(thb + (size_t)(t * 128 + n) * CA + cp) = v;
  }
  unsigned short* phb = phi + (size_t)b * MM * CA;
  for (int i = tid; i < 32 * 32; i += 512) {
    const int ca = i & 31, mx = i >> 5;
    const float v = fmaxf(
        fmaxf(bf2f(ol[32 + ca][2 * mx]), bf2f(ol[32 + ca][2 * mx + 1])),
        fmaxf(bf2f(ol[32 + ca][64 + 2 * mx]), bf2f(ol[32 + ca][64 + 2 * mx + 1])));
    phb[(size_t)(t * 32 + mx) * CA + ca] = f2bf(v);
  }
  // g2: m = t*32 + mx -> ((t*8 + (c>>4))*512 + ((mx>>3))*128 + (c&15)*8 + (mx&7)
  unsigned short* gb2 = g2 + (size_t)b * CH * MM;
  for (int i = tid; i < 128 * 32; i += 512) {
    const int mx = i & 31, c = i >> 5;
    const float v = fmaxf(
        fmaxf(bf2f(ol[64 + c][2 * mx]), bf2f(ol[64 + c][2 * mx + 1])),
        fmaxf(bf2f(ol[64 + c][64 + 2 * mx]), bf2f(ol[64 + c][64 + 2 * mx + 1])));
    gb2[(size_t)(t * 8 + (c >> 4)) * 512 + ((mx >> 3) & 3) * 128 + (c & 15) * 8 +
        (mx & 7)] = f2bf(v);
  }
}

// Flash attention, split-K pair-of-waves, fragment-contiguous V/W loads.
__global__ __launch_bounds__(256, 6) void k_attn_out(
    const unsigned short* __restrict__ theta, const unsigned short* __restrict__ phi,
    const unsigned short* __restrict__ g2, const unsigned short* __restrict__ wo2,
    const float* __restrict__ x, const float* __restrict__ gammap,
    float* __restrict__ out) {
  __shared__ unsigned short pl[4][16][72];  // [wave][n(16)][m(64)+pad8]
  __shared__ unsigned short ob[2][16][136]; // [pair][n(16)][c(128)+pad8] merge buf
  __shared__ float mlb[4][2][16];           // [wave][{m,l}][n]
  const int b = blockIdx.y;
  const int tid = threadIdx.x;
  const int wv = tid >> 6;
  const int pr = wv >> 1;      // pair id (owns an n-tile)
  const int h = wv & 1;        // key-half
  const int l = tid & 63;
  const int grp = l >> 4, col = l & 15;
  const int n0 = blockIdx.x * 32 + pr * 16;
  const s16x8 qf = *reinterpret_cast<const s16x8*>(
      theta + ((size_t)b * NN + n0 + col) * CA + grp * 8);
  f32x4 oacc[8];
#pragma unroll
  for (int t = 0; t < 8; ++t) oacc[t] = f32x4{0.f, 0.f, 0.f, 0.f};
  float mrow = -INFINITY, lrow = 0.f;
  const unsigned short* phb = phi + (size_t)b * MM * CA;
  const unsigned short* gb2 = g2 + (size_t)b * CH * MM;
  const f32x4 z4 = {0.f, 0.f, 0.f, 0.f};
#pragma unroll 1
  for (int it = 0; it < 8; ++it) {
    const int mc = h * 512 + it * 64;
    const s16x8 kf0 = *reinterpret_cast<const s16x8*>(phb + (size_t)(mc + col) * CA + grp * 8);
    const s16x8 kf1 = *reinterpret_cast<const s16x8*>(phb + (size_t)(mc + 16 + col) * CA + grp * 8);
    const s16x8 kf2 = *reinterpret_cast<const s16x8*>(phb + (size_t)(mc + 32 + col) * CA + grp * 8);
    const s16x8 kf3 = *reinterpret_cast<const s16x8*>(phb + (size_t)(mc + 48 + col) * CA + grp * 8);
    f32x4 s0 = __builtin_amdgcn_mfma_f32_16x16x32_bf16(kf0, qf, z4, 0, 0, 0);
    f32x4 s1 = __builtin_amdgcn_mfma_f32_16x16x32_bf16(kf1, qf, z4, 0, 0, 0);
    f32x4 s2 = __builtin_amdgcn_mfma_f32_16x16x32_bf16(kf2, qf, z4, 0, 0, 0);
    f32x4 s3 = __builtin_amdgcn_mfma_f32_16x16x32_bf16(kf3, qf, z4, 0, 0, 0);
    float cm = -INFINITY;
#pragma unroll
    for (int r = 0; r < 4; ++r)
      cm = fmaxf(cm, fmaxf(fmaxf(s0[r], s1[r]), fmaxf(s2[r], s3[r])));
    cm = fmaxf(cm, __shfl_xor(cm, 16));
    cm = fmaxf(cm, __shfl_xor(cm, 32));
    if (!__all(cm <= mrow + 8.f)) {  // defer-max (T13)
      const float mnew = fmaxf(mrow, cm);
      const float scale = __expf(mrow - mnew);
      lrow *= scale;
#pragma unroll
      for (int t = 0; t < 8; ++t) {
#pragma unroll
        for (int r = 0; r < 4; ++r) oacc[t][r] *= scale;
      }
      mrow = mnew;
    }
    float p0[4], p1[4], p2[4], p3[4];
    float cs = 0.f;
#pragma unroll
    for (int r = 0; r < 4; ++r) {
      p0[r] = __expf(s0[r] - mrow);
      p1[r] = __expf(s1[r] - mrow);
      p2[r] = __expf(s2[r] - mrow);
      p3[r] = __expf(s3[r] - mrow);
      cs += (p0[r] + p1[r]) + (p2[r] + p3[r]);
    }
    cs += __shfl_xor(cs, 16);
    cs += __shfl_xor(cs, 32);
    lrow += cs;
    *reinterpret_cast<uint2*>(&pl[wv][col][grp * 4]) =
        make_uint2((unsigned)f2bf(p0[0]) | ((unsigned)f2bf(p0[1]) << 16),
                   (unsigned)f2bf(p0[2]) | ((unsigned)f2bf(p0[3]) << 16));
    *reinterpret_cast<uint2*>(&pl[wv][col][16 + grp * 4]) =
        make_uint2((unsigned)f2bf(p1[0]) | ((unsigned)f2bf(p1[1]) << 16),
                   (unsigned)f2bf(p1[2]) | ((unsigned)f2bf(p1[3]) << 16));
    *reinterpret_cast<uint2*>(&pl[wv][col][32 + grp * 4]) =
        make_uint2((unsigned)f2bf(p2[0]) | ((unsigned)f2bf(p2[1]) << 16),
                   (unsigned)f2bf(p2[2]) | ((unsigned)f2bf(p2[3]) << 16));
    *reinterpret_cast<uint2*>(&pl[wv][col][48 + grp * 4]) =
        make_uint2((unsigned)f2bf(p3[0]) | ((unsigned)f2bf(p3[1]) << 16),
                   (unsigned)f2bf(p3[2]) | ((unsigned)f2bf(p3[3]) << 16));
    const s16x8 pfA = *reinterpret_cast<const s16x8*>(&pl[wv][col][grp * 8]);
    const s16x8 pfB = *reinterpret_cast<const s16x8*>(&pl[wv][col][32 + grp * 8]);
    // V^T fragments: 1KB fully-contiguous per (t, half) in g2 layout
    const unsigned short* gA = gb2 + (size_t)(mc >> 5) * 4096 + grp * 128 + col * 8;
#pragma unroll
    for (int t = 0; t < 8; ++t) {
      const s16x8 vfA = *reinterpret_cast<const s16x8*>(gA + t * 512);
      const s16x8 vfB = *reinterpret_cast<const s16x8*>(gA + 4096 + t * 512);
      oacc[t] = __builtin_amdgcn_mfma_f32_16x16x32_bf16(vfA, pfA, oacc[t], 0, 0, 0);
      oacc[t] = __builtin_amdgcn_mfma_f32_16x16x32_bf16(vfB, pfB, oacc[t], 0, 0, 0);
    }
  }
  // ---- split-K merge across the wave pair ----
  if (grp == 0) {
    mlb[wv][0][col] = mrow;
    mlb[wv][1][col] = lrow;
  }
  __syncthreads();
  const float mo = mlb[wv ^ 1][0][col];
  const float lo = mlb[wv ^ 1][1][col];
  const float mtot = fmaxf(mrow, mo);
  const float sc_self = __expf(mrow - mtot);
  const float ltot = lrow * sc_self + lo * __expf(mo - mtot);
  if (h == 1) {  // upper-half wave stages its scaled O
#pragma unroll
    for (int t = 0; t < 8; ++t) {
      const unsigned int lov = (unsigned)f2bf(oacc[t][0] * sc_self) |
                               ((unsigned)f2bf(oacc[t][1] * sc_self) << 16);
      const unsigned int hiv = (unsigned)f2bf(oacc[t][2] * sc_self) |
                               ((unsigned)f2bf(oacc[t][3] * sc_self) << 16);
      *reinterpret_cast<uint2*>(&ob[pr][col][t * 16 + grp * 4]) = make_uint2(lov, hiv);
    }
  }
  __syncthreads();
  if (h == 0) {  // lower-half wave merges + normalizes
    const float rinv = 1.f / ltot;
#pragma unroll
    for (int t = 0; t < 8; ++t) {
      float v[4];
#pragma unroll
      for (int q = 0; q < 4; ++q)
        v[q] = (oacc[t][q] * sc_self + bf2f(ob[pr][col][t * 16 + grp * 4 + q])) * rinv;
      const unsigned int lov = (unsigned)f2bf(v[0]) | ((unsigned)f2bf(v[1]) << 16);
      const unsigned int hiv = (unsigned)f2bf(v[2]) | ((unsigned)f2bf(v[3]) << 16);
      *reinterpret_cast<uint2*>(&ob[pr][col][t * 16 + grp * 4]) = make_uint2(lov, hiv);
    }
  }
  __syncthreads();
  // ---- fused out-projection: each wave of the pair does 8 of 16 row-tiles ----
  s16x8 of[4];
#pragma unroll
  for (int ks = 0; ks < 4; ++ks)
    of[ks] = *reinterpret_cast<const s16x8*>(&ob[pr][col][ks * 32 + grp * 8]);
  const float gamma = gammap[0];
  const float* xb2 = x + (size_t)b * CIN * NN;
  float* outb = out + (size_t)b * CIN * NN;
  const int t2base = h * 8;
#pragma unroll 1
  for (int t2i = 0; t2i < 8; ++t2i) {
    const int t2 = t2base + t2i;
    f32x4 a2 = {0.f, 0.f, 0.f, 0.f};
#pragma unroll
    for (int ks = 0; ks < 4; ++ks) {
      // wo2 fragment: 1KB contiguous
      const s16x8 wf = *reinterpret_cast<const s16x8*>(
          wo2 + (size_t)(t2 * 16 + ks * 4 + grp) * 128 + col * 8);
      a2 = __builtin_amdgcn_mfma_f32_16x16x32_bf16(wf, of[ks], a2, 0, 0, 0);
    }
#pragma unroll
    for (int r = 0; r < 4; ++r) {
      const size_t idx = (size_t)(t2 * 16 + grp * 4 + r) * NN + n0 + col;
      outb[idx] = fmaf(gamma, a2[r], xb2[idx]);
    }
  }
}

extern "C" void kernel_launch(void* const* d_in, const int* in_sizes, int n_in,
                              void* d_out, int out_size, void* d_ws, size_t ws_size,
                              hipStream_t stream) {
  const float* x = (const float*)d_in[0];
  const float* w_theta = (const float*)d_in[1];
  const float* w_phi = (const float*)d_in[2];
  const float* w_g = (const float*)d_in[3];
  const float* w_o = (const float*)d_in[4];
  const float* gamma = (const float*)d_in[5];
  float* out = (float*)d_out;
  char* ws = (char*)d_ws;
  unsigned short* theta = (unsigned short*)(ws + 0);
  unsigned short* phi = (unsigned short*)(ws + 4194304);
  unsigned short* g2 = (unsigned short*)(ws + 5242880);
  unsigned short* wo2 = (unsigned short*)(ws + 9437184);
  unsigned short* wcat = (unsigned short*)(ws + 9502720);

  k_wcvt<<<dim3(320), 256, 0, stream>>>(w_theta, w_phi, w_g, w_o, wcat, wo2);
  k_proj<<<dim3(NN / 128, NB), 512, 0, stream>>>(x, wcat, theta, phi, g2);
  k_attn_out<<<dim3(NN / 32, NB), 256, 0, stream>>>(theta, phi, g2, wo2, x, gamma, out);
}

// Round 8
// 136.008 us; speedup vs baseline: 1.6288x; 1.0327x over previous
//
#include <hip/hip_runtime.h>
#include <hip/hip_bf16.h>

#define NB 16
#define CIN 256
#define CA 32
#define CH 128
#define NN 4096
#define MM 1024

typedef __attribute__((ext_vector_type(8))) short s16x8;
typedef __attribute__((ext_vector_type(4))) float f32x4;

static __device__ __forceinline__ unsigned short f2bf(float x) {
  __hip_bfloat16 h = __float2bfloat16(x);
  return __builtin_bit_cast(unsigned short, h);
}
static __device__ __forceinline__ float bf2f(unsigned short u) {
  unsigned int v = ((unsigned int)u) << 16;
  return __builtin_bit_cast(float, v);
}

// Build wcat (192x256 bf16 = [w_theta; w_phi; w_g]) and wo2 (fragment-packed).
__global__ __launch_bounds__(256) void k_wcvt(const float* __restrict__ w_theta,
                                              const float* __restrict__ w_phi,
                                              const float* __restrict__ w_g,
                                              const float* __restrict__ w_o,
                                              unsigned short* __restrict__ wcat,
                                              unsigned short* __restrict__ wo2) {
  const int i = blockIdx.x * 256 + threadIdx.x;
  if (i < 8192) wcat[i] = f2bf(w_theta[i]);
  else if (i < 16384) wcat[i] = f2bf(w_phi[i - 8192]);
  else if (i < 49152) wcat[i] = f2bf(w_g[i - 16384]);
  else {
    const int w = i - 49152;
    const int c_out = w >> 7, k = w & 127;
    const int dst = (((c_out >> 4) * 16) + ((k >> 5) * 4) + ((k >> 3) & 3)) * 128 +
                    ((c_out & 15) << 3) + (k & 7);
    wo2[dst] = f2bf(w_o[w]);
  }
}

// MFMA projection: conv = wcat @ x_b (192 x 4096 per batch), staged in LDS,
// then theta / pooled phi / pooled fragment-packed g2.
__global__ __launch_bounds__(512) void k_proj(const float* __restrict__ x,
                                              const unsigned short* __restrict__ wcat,
                                              unsigned short* __restrict__ theta,
                                              unsigned short* __restrict__ phi,
                                              unsigned short* __restrict__ g2) {
  __shared__ unsigned short ol[192][136];
  const int b = blockIdx.y;
  const int t = blockIdx.x;
  const int tid = threadIdx.x;
  const int wv = tid >> 6;
  const int l = tid & 63;
  const int grp = l >> 4, col = l & 15;
  const int n0 = t * 128 + wv * 16;
  const float* xb = x + (size_t)b * CIN * NN;
  f32x4 acc[12];
#pragma unroll
  for (int r = 0; r < 12; ++r) acc[r] = f32x4{0.f, 0.f, 0.f, 0.f};
#pragma unroll 1
  for (int kc = 0; kc < 8; ++kc) {
    const int c0 = kc * 32 + grp * 8;
    s16x8 bfrag;
#pragma unroll
    for (int j = 0; j < 8; ++j)
      bfrag[j] = (short)f2bf(xb[(size_t)(c0 + j) * NN + n0 + col]);
#pragma unroll
    for (int r = 0; r < 12; ++r) {
      const s16x8 af = *reinterpret_cast<const s16x8*>(
          wcat + (size_t)(r * 16 + col) * CIN + c0);
      acc[r] = __builtin_amdgcn_mfma_f32_16x16x32_bf16(af, bfrag, acc[r], 0, 0, 0);
    }
  }
#pragma unroll
  for (int r = 0; r < 12; ++r)
#pragma unroll
    for (int q = 0; q < 4; ++q)
      ol[r * 16 + grp * 4 + q][wv * 16 + col] = f2bf(acc[r][q]);
  __syncthreads();
  unsigned short* thb = theta + (size_t)b * NN * CA;
  for (int i = tid; i < 128 * 16; i += 512) {
    const int n = i >> 4, cp = (i & 15) << 1;
    const unsigned int v = (unsigned)ol[cp][n] | ((unsigned)ol[cp + 1][n] << 16);
    *reinterpret_cast<unsigned int*>(thb + (size_t)(t * 128 + n) * CA + cp) = v;
  }
  unsigned short* phb = phi + (size_t)b * MM * CA;
  for (int i = tid; i < 32 * 32; i += 512) {
    const int ca = i & 31, mx = i >> 5;
    const float v = fmaxf(
        fmaxf(bf2f(ol[32 + ca][2 * mx]), bf2f(ol[32 + ca][2 * mx + 1])),
        fmaxf(bf2f(ol[32 + ca][64 + 2 * mx]), bf2f(ol[32 + ca][64 + 2 * mx + 1])));
    phb[(size_t)(t * 32 + mx) * CA + ca] = f2bf(v);
  }
  unsigned short* gb2 = g2 + (size_t)b * CH * MM;
  for (int i = tid; i < 128 * 32; i += 512) {
    const int mx = i & 31, c = i >> 5;
    const float v = fmaxf(
        fmaxf(bf2f(ol[64 + c][2 * mx]), bf2f(ol[64 + c][2 * mx + 1])),
        fmaxf(bf2f(ol[64 + c][64 + 2 * mx]), bf2f(ol[64 + c][64 + 2 * mx + 1])));
    gb2[(size_t)(t * 8 + (c >> 4)) * 512 + ((mx >> 3) & 3) * 128 + (c & 15) * 8 +
        (mx & 7)] = f2bf(v);
  }
}

// Flash attention, split-K pair-of-waves, DOUBLE-Q: each wave owns 32 n-cols
// (two 16-col Q fragments), so K/V fragment loads feed 2x the MFMA work.
__global__ __launch_bounds__(256, 3) void k_attn_out(
    const unsigned short* __restrict__ theta, const unsigned short* __restrict__ phi,
    const unsigned short* __restrict__ g2, const unsigned short* __restrict__ wo2,
    const float* __restrict__ x, const float* __restrict__ gammap,
    float* __restrict__ out) {
  __shared__ unsigned short pl[4][2][16][72];  // [wave][nt][n(16)][m(64)+pad]
  __shared__ unsigned short ob[2][32][136];    // [pair][n(32)][c(128)+pad]
  __shared__ float mlb[4][2][32];              // [wave][{m,l}][nt*16+n]
  const int b = blockIdx.y;
  const int tid = threadIdx.x;
  const int wv = tid >> 6;
  const int pr = wv >> 1;  // pair id (owns a 32-col n-tile)
  const int h = wv & 1;    // key-half
  const int l = tid & 63;
  const int grp = l >> 4, col = l & 15;
  const int n0 = blockIdx.x * 64 + pr * 32;
  const unsigned short* thb = theta + (size_t)b * NN * CA;
  const s16x8 qf0 = *reinterpret_cast<const s16x8*>(thb + (size_t)(n0 + col) * CA + grp * 8);
  const s16x8 qf1 = *reinterpret_cast<const s16x8*>(thb + (size_t)(n0 + 16 + col) * CA + grp * 8);
  f32x4 oa0[8], oa1[8];
#pragma unroll
  for (int t = 0; t < 8; ++t) {
    oa0[t] = f32x4{0.f, 0.f, 0.f, 0.f};
    oa1[t] = f32x4{0.f, 0.f, 0.f, 0.f};
  }
  float m0 = -INFINITY, l0 = 0.f, m1 = -INFINITY, l1 = 0.f;
  const unsigned short* phb = phi + (size_t)b * MM * CA;
  const unsigned short* gb2 = g2 + (size_t)b * CH * MM;
  const f32x4 z4 = {0.f, 0.f, 0.f, 0.f};
#pragma unroll 1
  for (int it = 0; it < 8; ++it) {
    const int mc = h * 512 + it * 64;
    const s16x8 kf0 = *reinterpret_cast<const s16x8*>(phb + (size_t)(mc + col) * CA + grp * 8);
    const s16x8 kf1 = *reinterpret_cast<const s16x8*>(phb + (size_t)(mc + 16 + col) * CA + grp * 8);
    const s16x8 kf2 = *reinterpret_cast<const s16x8*>(phb + (size_t)(mc + 32 + col) * CA + grp * 8);
    const s16x8 kf3 = *reinterpret_cast<const s16x8*>(phb + (size_t)(mc + 48 + col) * CA + grp * 8);
    f32x4 s00 = __builtin_amdgcn_mfma_f32_16x16x32_bf16(kf0, qf0, z4, 0, 0, 0);
    f32x4 s01 = __builtin_amdgcn_mfma_f32_16x16x32_bf16(kf1, qf0, z4, 0, 0, 0);
    f32x4 s02 = __builtin_amdgcn_mfma_f32_16x16x32_bf16(kf2, qf0, z4, 0, 0, 0);
    f32x4 s03 = __builtin_amdgcn_mfma_f32_16x16x32_bf16(kf3, qf0, z4, 0, 0, 0);
    f32x4 s10 = __builtin_amdgcn_mfma_f32_16x16x32_bf16(kf0, qf1, z4, 0, 0, 0);
    f32x4 s11 = __builtin_amdgcn_mfma_f32_16x16x32_bf16(kf1, qf1, z4, 0, 0, 0);
    f32x4 s12 = __builtin_amdgcn_mfma_f32_16x16x32_bf16(kf2, qf1, z4, 0, 0, 0);
    f32x4 s13 = __builtin_amdgcn_mfma_f32_16x16x32_bf16(kf3, qf1, z4, 0, 0, 0);
    float cm0 = -INFINITY, cm1 = -INFINITY;
#pragma unroll
    for (int r = 0; r < 4; ++r) {
      cm0 = fmaxf(cm0, fmaxf(fmaxf(s00[r], s01[r]), fmaxf(s02[r], s03[r])));
      cm1 = fmaxf(cm1, fmaxf(fmaxf(s10[r], s11[r]), fmaxf(s12[r], s13[r])));
    }
    cm0 = fmaxf(cm0, __shfl_xor(cm0, 16));
    cm0 = fmaxf(cm0, __shfl_xor(cm0, 32));
    cm1 = fmaxf(cm1, __shfl_xor(cm1, 16));
    cm1 = fmaxf(cm1, __shfl_xor(cm1, 32));
    if (!__all(cm0 <= m0 + 8.f && cm1 <= m1 + 8.f)) {  // defer-max (T13)
      const float mn0 = fmaxf(m0, cm0), mn1 = fmaxf(m1, cm1);
      const float sc0 = __expf(m0 - mn0), sc1 = __expf(m1 - mn1);
      l0 *= sc0;
      l1 *= sc1;
#pragma unroll
      for (int t = 0; t < 8; ++t) {
#pragma unroll
        for (int r = 0; r < 4; ++r) {
          oa0[t][r] *= sc0;
          oa1[t][r] *= sc1;
        }
      }
      m0 = mn0;
      m1 = mn1;
    }
    {  // nt0 softmax + P staging
      float p0[4], p1[4], p2[4], p3[4];
      float cs = 0.f;
#pragma unroll
      for (int r = 0; r < 4; ++r) {
        p0[r] = __expf(s00[r] - m0);
        p1[r] = __expf(s01[r] - m0);
        p2[r] = __expf(s02[r] - m0);
        p3[r] = __expf(s03[r] - m0);
        cs += (p0[r] + p1[r]) + (p2[r] + p3[r]);
      }
      cs += __shfl_xor(cs, 16);
      cs += __shfl_xor(cs, 32);
      l0 += cs;
      *reinterpret_cast<uint2*>(&pl[wv][0][col][grp * 4]) =
          make_uint2((unsigned)f2bf(p0[0]) | ((unsigned)f2bf(p0[1]) << 16),
                     (unsigned)f2bf(p0[2]) | ((unsigned)f2bf(p0[3]) << 16));
      *reinterpret_cast<uint2*>(&pl[wv][0][col][16 + grp * 4]) =
          make_uint2((unsigned)f2bf(p1[0]) | ((unsigned)f2bf(p1[1]) << 16),
                     (unsigned)f2bf(p1[2]) | ((unsigned)f2bf(p1[3]) << 16));
      *reinterpret_cast<uint2*>(&pl[wv][0][col][32 + grp * 4]) =
          make_uint2((unsigned)f2bf(p2[0]) | ((unsigned)f2bf(p2[1]) << 16),
                     (unsigned)f2bf(p2[2]) | ((unsigned)f2bf(p2[3]) << 16));
      *reinterpret_cast<uint2*>(&pl[wv][0][col][48 + grp * 4]) =
          make_uint2((unsigned)f2bf(p3[0]) | ((unsigned)f2bf(p3[1]) << 16),
                     (unsigned)f2bf(p3[2]) | ((unsigned)f2bf(p3[3]) << 16));
    }
    {  // nt1 softmax + P staging
      float p0[4], p1[4], p2[4], p3[4];
      float cs = 0.f;
#pragma unroll
      for (int r = 0; r < 4; ++r) {
        p0[r] = __expf(s10[r] - m1);
        p1[r] = __expf(s11[r] - m1);
        p2[r] = __expf(s12[r] - m1);
        p3[r] = __expf(s13[r] - m1);
        cs += (p0[r] + p1[r]) + (p2[r] + p3[r]);
      }
      cs += __shfl_xor(cs, 16);
      cs += __shfl_xor(cs, 32);
      l1 += cs;
      *reinterpret_cast<uint2*>(&pl[wv][1][col][grp * 4]) =
          make_uint2((unsigned)f2bf(p0[0]) | ((unsigned)f2bf(p0[1]) << 16),
                     (unsigned)f2bf(p0[2]) | ((unsigned)f2bf(p0[3]) << 16));
      *reinterpret_cast<uint2*>(&pl[wv][1][col][16 + grp * 4]) =
          make_uint2((unsigned)f2bf(p1[0]) | ((unsigned)f2bf(p1[1]) << 16),
                     (unsigned)f2bf(p1[2]) | ((unsigned)f2bf(p1[3]) << 16));
      *reinterpret_cast<uint2*>(&pl[wv][1][col][32 + grp * 4]) =
          make_uint2((unsigned)f2bf(p2[0]) | ((unsigned)f2bf(p2[1]) << 16),
                     (unsigned)f2bf(p2[2]) | ((unsigned)f2bf(p2[3]) << 16));
      *reinterpret_cast<uint2*>(&pl[wv][1][col][48 + grp * 4]) =
          make_uint2((unsigned)f2bf(p3[0]) | ((unsigned)f2bf(p3[1]) << 16),
                     (unsigned)f2bf(p3[2]) | ((unsigned)f2bf(p3[3]) << 16));
    }
    const s16x8 pfA0 = *reinterpret_cast<const s16x8*>(&pl[wv][0][col][grp * 8]);
    const s16x8 pfB0 = *reinterpret_cast<const s16x8*>(&pl[wv][0][col][32 + grp * 8]);
    const s16x8 pfA1 = *reinterpret_cast<const s16x8*>(&pl[wv][1][col][grp * 8]);
    const s16x8 pfB1 = *reinterpret_cast<const s16x8*>(&pl[wv][1][col][32 + grp * 8]);
    const unsigned short* gA = gb2 + (size_t)(mc >> 5) * 4096 + grp * 128 + col * 8;
#pragma unroll
    for (int t = 0; t < 8; ++t) {
      const s16x8 vfA = *reinterpret_cast<const s16x8*>(gA + t * 512);
      const s16x8 vfB = *reinterpret_cast<const s16x8*>(gA + 4096 + t * 512);
      oa0[t] = __builtin_amdgcn_mfma_f32_16x16x32_bf16(vfA, pfA0, oa0[t], 0, 0, 0);
      oa0[t] = __builtin_amdgcn_mfma_f32_16x16x32_bf16(vfB, pfB0, oa0[t], 0, 0, 0);
      oa1[t] = __builtin_amdgcn_mfma_f32_16x16x32_bf16(vfA, pfA1, oa1[t], 0, 0, 0);
      oa1[t] = __builtin_amdgcn_mfma_f32_16x16x32_bf16(vfB, pfB1, oa1[t], 0, 0, 0);
    }
  }
  // ---- split-K merge across the wave pair ----
  if (grp == 0) {
    mlb[wv][0][col] = m0;
    mlb[wv][1][col] = l0;
    mlb[wv][0][16 + col] = m1;
    mlb[wv][1][16 + col] = l1;
  }
  __syncthreads();
  const float mo0 = mlb[wv ^ 1][0][col], lo0 = mlb[wv ^ 1][1][col];
  const float mo1 = mlb[wv ^ 1][0][16 + col], lo1 = mlb[wv ^ 1][1][16 + col];
  const float mt0 = fmaxf(m0, mo0), mt1 = fmaxf(m1, mo1);
  const float sc0 = __expf(m0 - mt0), sc1 = __expf(m1 - mt1);
  const float lt0 = l0 * sc0 + lo0 * __expf(mo0 - mt0);
  const float lt1 = l1 * sc1 + lo1 * __expf(mo1 - mt1);
  if (h == 1) {  // stage scaled O for both n-tiles
#pragma unroll
    for (int t = 0; t < 8; ++t) {
      *reinterpret_cast<uint2*>(&ob[pr][col][t * 16 + grp * 4]) =
          make_uint2((unsigned)f2bf(oa0[t][0] * sc0) | ((unsigned)f2bf(oa0[t][1] * sc0) << 16),
                     (unsigned)f2bf(oa0[t][2] * sc0) | ((unsigned)f2bf(oa0[t][3] * sc0) << 16));
      *reinterpret_cast<uint2*>(&ob[pr][16 + col][t * 16 + grp * 4]) =
          make_uint2((unsigned)f2bf(oa1[t][0] * sc1) | ((unsigned)f2bf(oa1[t][1] * sc1) << 16),
                     (unsigned)f2bf(oa1[t][2] * sc1) | ((unsigned)f2bf(oa1[t][3] * sc1) << 16));
    }
  }
  __syncthreads();
  if (h == 0) {  // merge + normalize
    const float ri0 = 1.f / lt0, ri1 = 1.f / lt1;
#pragma unroll
    for (int t = 0; t < 8; ++t) {
      float v0[4], v1[4];
#pragma unroll
      for (int q = 0; q < 4; ++q) {
        v0[q] = (oa0[t][q] * sc0 + bf2f(ob[pr][col][t * 16 + grp * 4 + q])) * ri0;
        v1[q] = (oa1[t][q] * sc1 + bf2f(ob[pr][16 + col][t * 16 + grp * 4 + q])) * ri1;
      }
      *reinterpret_cast<uint2*>(&ob[pr][col][t * 16 + grp * 4]) =
          make_uint2((unsigned)f2bf(v0[0]) | ((unsigned)f2bf(v0[1]) << 16),
                     (unsigned)f2bf(v0[2]) | ((unsigned)f2bf(v0[3]) << 16));
      *reinterpret_cast<uint2*>(&ob[pr][16 + col][t * 16 + grp * 4]) =
          make_uint2((unsigned)f2bf(v1[0]) | ((unsigned)f2bf(v1[1]) << 16),
                     (unsigned)f2bf(v1[2]) | ((unsigned)f2bf(v1[3]) << 16));
    }
  }
  __syncthreads();
  // ---- fused out-projection: wf reused across both n-tiles ----
  s16x8 of0[4], of1[4];
#pragma unroll
  for (int ks = 0; ks < 4; ++ks) {
    of0[ks] = *reinterpret_cast<const s16x8*>(&ob[pr][col][ks * 32 + grp * 8]);
    of1[ks] = *reinterpret_cast<const s16x8*>(&ob[pr][16 + col][ks * 32 + grp * 8]);
  }
  const float gamma = gammap[0];
  const float* xb2 = x + (size_t)b * CIN * NN;
  float* outb = out + (size_t)b * CIN * NN;
  const int t2base = h * 8;
#pragma unroll 1
  for (int t2i = 0; t2i < 8; ++t2i) {
    const int t2 = t2base + t2i;
    f32x4 a20 = {0.f, 0.f, 0.f, 0.f};
    f32x4 a21 = {0.f, 0.f, 0.f, 0.f};
#pragma unroll
    for (int ks = 0; ks < 4; ++ks) {
      const s16x8 wf = *reinterpret_cast<const s16x8*>(
          wo2 + (size_t)(t2 * 16 + ks * 4 + grp) * 128 + col * 8);
      a20 = __builtin_amdgcn_mfma_f32_16x16x32_bf16(wf, of0[ks], a20, 0, 0, 0);
      a21 = __builtin_amdgcn_mfma_f32_16x16x32_bf16(wf, of1[ks], a21, 0, 0, 0);
    }
#pragma unroll
    for (int r = 0; r < 4; ++r) {
      const size_t idx = (size_t)(t2 * 16 + grp * 4 + r) * NN + n0 + col;
      outb[idx] = fmaf(gamma, a20[r], xb2[idx]);
      outb[idx + 16] = fmaf(gamma, a21[r], xb2[idx + 16]);
    }
  }
}

extern "C" void kernel_launch(void* const* d_in, const int* in_sizes, int n_in,
                              void* d_out, int out_size, void* d_ws, size_t ws_size,
                              hipStream_t stream) {
  const float* x = (const float*)d_in[0];
  const float* w_theta = (const float*)d_in[1];
  const float* w_phi = (const float*)d_in[2];
  const float* w_g = (const float*)d_in[3];
  const float* w_o = (const float*)d_in[4];
  const float* gamma = (const float*)d_in[5];
  float* out = (float*)d_out;
  char* ws = (char*)d_ws;
  unsigned short* theta = (unsigned short*)(ws + 0);
  unsigned short* phi = (unsigned short*)(ws + 4194304);
  unsigned short* g2 = (unsigned short*)(ws + 5242880);
  unsigned short* wo2 = (unsigned short*)(ws + 9437184);
  unsigned short* wcat = (unsigned short*)(ws + 9502720);

  k_wcvt<<<dim3(320), 256, 0, stream>>>(w_theta, w_phi, w_g, w_o, wcat, wo2);
  k_proj<<<dim3(NN / 128, NB), 512, 0, stream>>>(x, wcat, theta, phi, g2);
  k_attn_out<<<dim3(NN / 64, NB), 256, 0, stream>>>(theta, phi, g2, wo2, x, gamma, out);
}

// Round 9
// 111.797 us; speedup vs baseline: 1.9815x; 1.2166x over previous
//
#include <hip/hip_runtime.h>
#include <hip/hip_bf16.h>

#define NB 16
#define CIN 256
#define CA 32
#define CH 128
#define NN 4096
#define MM 1024

typedef __attribute__((ext_vector_type(8))) short s16x8;
typedef __attribute__((ext_vector_type(4))) float f32x4;

static __device__ __forceinline__ unsigned short f2bf(float x) {
  __hip_bfloat16 h = __float2bfloat16(x);
  return __builtin_bit_cast(unsigned short, h);
}
static __device__ __forceinline__ float bf2f(unsigned short u) {
  unsigned int v = ((unsigned int)u) << 16;
  return __builtin_bit_cast(float, v);
}
// async global->LDS DMA, 16B per lane; lds dst is wave-uniform base + lane*16
static __device__ __forceinline__ void gload_lds16(const void* g, void* s) {
  __builtin_amdgcn_global_load_lds(
      (const __attribute__((address_space(1))) unsigned int*)g,
      (__attribute__((address_space(3))) unsigned int*)s, 16, 0, 0);
}

// Build wcat (192x256 bf16 = [w_theta; w_phi; w_g]) and wo2 (fragment-packed).
__global__ __launch_bounds__(256) void k_wcvt(const float* __restrict__ w_theta,
                                              const float* __restrict__ w_phi,
                                              const float* __restrict__ w_g,
                                              const float* __restrict__ w_o,
                                              unsigned short* __restrict__ wcat,
                                              unsigned short* __restrict__ wo2) {
  const int i = blockIdx.x * 256 + threadIdx.x;
  if (i < 8192) wcat[i] = f2bf(w_theta[i]);
  else if (i < 16384) wcat[i] = f2bf(w_phi[i - 8192]);
  else if (i < 49152) wcat[i] = f2bf(w_g[i - 16384]);
  else {
    const int w = i - 49152;
    const int c_out = w >> 7, k = w & 127;
    const int dst = (((c_out >> 4) * 16) + ((k >> 5) * 4) + ((k >> 3) & 3)) * 128 +
                    ((c_out & 15) << 3) + (k & 7);
    wo2[dst] = f2bf(w_o[w]);
  }
}

// MFMA projection. Outputs:
//  theta (b,n,ca) row-major;
//  phi2 fragment-packed: (m,ca) -> (m>>4)*512 + (ca>>3)*128 + (m&15)*8 + (ca&7)
//  g2 fragment-packed:   (c,m)  -> ((m>>5)*8 + (c>>4))*512 + ((m>>3)&3)*128 + (c&15)*8 + (m&7)
__global__ __launch_bounds__(512) void k_proj(const float* __restrict__ x,
                                              const unsigned short* __restrict__ wcat,
                                              unsigned short* __restrict__ theta,
                                              unsigned short* __restrict__ phi2,
                                              unsigned short* __restrict__ g2) {
  __shared__ unsigned short ol[192][136];
  const int b = blockIdx.y;
  const int t = blockIdx.x;
  const int tid = threadIdx.x;
  const int wv = tid >> 6;
  const int l = tid & 63;
  const int grp = l >> 4, col = l & 15;
  const int n0 = t * 128 + wv * 16;
  const float* xb = x + (size_t)b * CIN * NN;
  f32x4 acc[12];
#pragma unroll
  for (int r = 0; r < 12; ++r) acc[r] = f32x4{0.f, 0.f, 0.f, 0.f};
#pragma unroll 1
  for (int kc = 0; kc < 8; ++kc) {
    const int c0 = kc * 32 + grp * 8;
    s16x8 bfrag;
#pragma unroll
    for (int j = 0; j < 8; ++j)
      bfrag[j] = (short)f2bf(xb[(size_t)(c0 + j) * NN + n0 + col]);
#pragma unroll
    for (int r = 0; r < 12; ++r) {
      const s16x8 af = *reinterpret_cast<const s16x8*>(
          wcat + (size_t)(r * 16 + col) * CIN + c0);
      acc[r] = __builtin_amdgcn_mfma_f32_16x16x32_bf16(af, bfrag, acc[r], 0, 0, 0);
    }
  }
#pragma unroll
  for (int r = 0; r < 12; ++r)
#pragma unroll
    for (int q = 0; q < 4; ++q)
      ol[r * 16 + grp * 4 + q][wv * 16 + col] = f2bf(acc[r][q]);
  __syncthreads();
  unsigned short* thb = theta + (size_t)b * NN * CA;
  for (int i = tid; i < 128 * 16; i += 512) {
    const int n = i >> 4, cp = (i & 15) << 1;
    const unsigned int v = (unsigned)ol[cp][n] | ((unsigned)ol[cp + 1][n] << 16);
    *reinterpret_cast<unsigned int*>(thb + (size_t)(t * 128 + n) * CA + cp) = v;
  }
  unsigned short* phb2 = phi2 + (size_t)b * MM * CA;
  for (int i = tid; i < 32 * 32; i += 512) {
    const int ca = i & 31, mx = i >> 5;
    const float v = fmaxf(
        fmaxf(bf2f(ol[32 + ca][2 * mx]), bf2f(ol[32 + ca][2 * mx + 1])),
        fmaxf(bf2f(ol[32 + ca][64 + 2 * mx]), bf2f(ol[32 + ca][64 + 2 * mx + 1])));
    const int m = t * 32 + mx;
    phb2[(m >> 4) * 512 + (ca >> 3) * 128 + (m & 15) * 8 + (ca & 7)] = f2bf(v);
  }
  unsigned short* gb2 = g2 + (size_t)b * CH * MM;
  for (int i = tid; i < 128 * 32; i += 512) {
    const int mx = i & 31, c = i >> 5;
    const float v = fmaxf(
        fmaxf(bf2f(ol[64 + c][2 * mx]), bf2f(ol[64 + c][2 * mx + 1])),
        fmaxf(bf2f(ol[64 + c][64 + 2 * mx]), bf2f(ol[64 + c][64 + 2 * mx + 1])));
    gb2[(size_t)(t * 8 + (c >> 4)) * 512 + ((mx >> 3) & 3) * 128 + (c & 15) * 8 +
        (mx & 7)] = f2bf(v);
  }
}

// Flash attention v3: 4 waves x 32 n-cols; all waves share LDS-staged K/V
// tiles (64 keys: K 4KB + V 16KB) DMA'd via global_load_lds, double-buffered.
__global__ __launch_bounds__(256, 2) void k_attn_out(
    const unsigned short* __restrict__ theta, const unsigned short* __restrict__ phi2,
    const unsigned short* __restrict__ g2, const unsigned short* __restrict__ wo2,
    const float* __restrict__ x, const float* __restrict__ gammap,
    float* __restrict__ out) {
  __shared__ __align__(16) unsigned short kv[2][10240];   // [buf][K 2048 | V 8192]
  __shared__ __align__(16) unsigned short pl[4][2][16][72];
  const int b = blockIdx.y;
  const int tid = threadIdx.x;
  const int wv = tid >> 6;
  const int l = tid & 63;
  const int grp = l >> 4, col = l & 15;
  const int n0 = blockIdx.x * 128 + wv * 32;
  const unsigned short* thb = theta + (size_t)b * NN * CA;
  const unsigned short* ph2b = phi2 + (size_t)b * MM * CA;
  const unsigned short* gb2 = g2 + (size_t)b * CH * MM;
  const s16x8 qf0 = *reinterpret_cast<const s16x8*>(thb + (size_t)(n0 + col) * CA + grp * 8);
  const s16x8 qf1 = *reinterpret_cast<const s16x8*>(thb + (size_t)(n0 + 16 + col) * CA + grp * 8);

  // stage 64-key tile: K = phi2 2048 shorts, V = g2 8192 shorts (both contiguous)
  auto STAGE = [&](int buf, int tile) {
    const int mc = tile * 64;
    const unsigned short* ksrc = ph2b + (mc >> 4) * 512;
    const unsigned short* vsrc = gb2 + (size_t)(mc >> 5) * 4096;
#pragma unroll
    for (int q = 0; q < 5; ++q) {
      const int i = wv * 5 + q;  // 20 x 1KB DMA instrs split across 4 waves
      const unsigned short* src = (i < 4) ? (ksrc + i * 512) : (vsrc + (i - 4) * 512);
      gload_lds16(src + (size_t)l * 8, &kv[buf][i * 512]);
    }
  };

  f32x4 oa0[8], oa1[8];
#pragma unroll
  for (int t = 0; t < 8; ++t) {
    oa0[t] = f32x4{0.f, 0.f, 0.f, 0.f};
    oa1[t] = f32x4{0.f, 0.f, 0.f, 0.f};
  }
  float m0 = -INFINITY, l0 = 0.f, m1 = -INFINITY, l1 = 0.f;
  const f32x4 z4 = {0.f, 0.f, 0.f, 0.f};

  STAGE(0, 0);
  __syncthreads();
#pragma unroll 1
  for (int it = 0; it < 16; ++it) {
    const int cur = it & 1;
    if (it < 15) STAGE(cur ^ 1, it + 1);  // fire-and-forget DMA for next tile
    const unsigned short* kb = &kv[cur][0];
    const unsigned short* vb = &kv[cur][2048];
    const int fo = grp * 128 + col * 8;  // fragment-local offset (shorts)
    const s16x8 kf0 = *reinterpret_cast<const s16x8*>(kb + 0 * 512 + fo);
    const s16x8 kf1 = *reinterpret_cast<const s16x8*>(kb + 1 * 512 + fo);
    const s16x8 kf2 = *reinterpret_cast<const s16x8*>(kb + 2 * 512 + fo);
    const s16x8 kf3 = *reinterpret_cast<const s16x8*>(kb + 3 * 512 + fo);
    f32x4 s00 = __builtin_amdgcn_mfma_f32_16x16x32_bf16(kf0, qf0, z4, 0, 0, 0);
    f32x4 s01 = __builtin_amdgcn_mfma_f32_16x16x32_bf16(kf1, qf0, z4, 0, 0, 0);
    f32x4 s02 = __builtin_amdgcn_mfma_f32_16x16x32_bf16(kf2, qf0, z4, 0, 0, 0);
    f32x4 s03 = __builtin_amdgcn_mfma_f32_16x16x32_bf16(kf3, qf0, z4, 0, 0, 0);
    f32x4 s10 = __builtin_amdgcn_mfma_f32_16x16x32_bf16(kf0, qf1, z4, 0, 0, 0);
    f32x4 s11 = __builtin_amdgcn_mfma_f32_16x16x32_bf16(kf1, qf1, z4, 0, 0, 0);
    f32x4 s12 = __builtin_amdgcn_mfma_f32_16x16x32_bf16(kf2, qf1, z4, 0, 0, 0);
    f32x4 s13 = __builtin_amdgcn_mfma_f32_16x16x32_bf16(kf3, qf1, z4, 0, 0, 0);
    float cm0 = -INFINITY, cm1 = -INFINITY;
#pragma unroll
    for (int r = 0; r < 4; ++r) {
      cm0 = fmaxf(cm0, fmaxf(fmaxf(s00[r], s01[r]), fmaxf(s02[r], s03[r])));
      cm1 = fmaxf(cm1, fmaxf(fmaxf(s10[r], s11[r]), fmaxf(s12[r], s13[r])));
    }
    cm0 = fmaxf(cm0, __shfl_xor(cm0, 16));
    cm0 = fmaxf(cm0, __shfl_xor(cm0, 32));
    cm1 = fmaxf(cm1, __shfl_xor(cm1, 16));
    cm1 = fmaxf(cm1, __shfl_xor(cm1, 32));
    if (!__all(cm0 <= m0 + 8.f && cm1 <= m1 + 8.f)) {  // defer-max (T13)
      const float mn0 = fmaxf(m0, cm0), mn1 = fmaxf(m1, cm1);
      const float sc0 = __expf(m0 - mn0), sc1 = __expf(m1 - mn1);
      l0 *= sc0;
      l1 *= sc1;
#pragma unroll
      for (int t = 0; t < 8; ++t) {
#pragma unroll
        for (int r = 0; r < 4; ++r) {
          oa0[t][r] *= sc0;
          oa1[t][r] *= sc1;
        }
      }
      m0 = mn0;
      m1 = mn1;
    }
    {
      float p0[4], p1[4], p2[4], p3[4];
      float cs = 0.f;
#pragma unroll
      for (int r = 0; r < 4; ++r) {
        p0[r] = __expf(s00[r] - m0);
        p1[r] = __expf(s01[r] - m0);
        p2[r] = __expf(s02[r] - m0);
        p3[r] = __expf(s03[r] - m0);
        cs += (p0[r] + p1[r]) + (p2[r] + p3[r]);
      }
      cs += __shfl_xor(cs, 16);
      cs += __shfl_xor(cs, 32);
      l0 += cs;
      *reinterpret_cast<uint2*>(&pl[wv][0][col][grp * 4]) =
          make_uint2((unsigned)f2bf(p0[0]) | ((unsigned)f2bf(p0[1]) << 16),
                     (unsigned)f2bf(p0[2]) | ((unsigned)f2bf(p0[3]) << 16));
      *reinterpret_cast<uint2*>(&pl[wv][0][col][16 + grp * 4]) =
          make_uint2((unsigned)f2bf(p1[0]) | ((unsigned)f2bf(p1[1]) << 16),
                     (unsigned)f2bf(p1[2]) | ((unsigned)f2bf(p1[3]) << 16));
      *reinterpret_cast<uint2*>(&pl[wv][0][col][32 + grp * 4]) =
          make_uint2((unsigned)f2bf(p2[0]) | ((unsigned)f2bf(p2[1]) << 16),
                     (unsigned)f2bf(p2[2]) | ((unsigned)f2bf(p2[3]) << 16));
      *reinterpret_cast<uint2*>(&pl[wv][0][col][48 + grp * 4]) =
          make_uint2((unsigned)f2bf(p3[0]) | ((unsigned)f2bf(p3[1]) << 16),
                     (unsigned)f2bf(p3[2]) | ((unsigned)f2bf(p3[3]) << 16));
    }
    {
      float p0[4], p1[4], p2[4], p3[4];
      float cs = 0.f;
#pragma unroll
      for (int r = 0; r < 4; ++r) {
        p0[r] = __expf(s10[r] - m1);
        p1[r] = __expf(s11[r] - m1);
        p2[r] = __expf(s12[r] - m1);
        p3[r] = __expf(s13[r] - m1);
        cs += (p0[r] + p1[r]) + (p2[r] + p3[r]);
      }
      cs += __shfl_xor(cs, 16);
      cs += __shfl_xor(cs, 32);
      l1 += cs;
      *reinterpret_cast<uint2*>(&pl[wv][1][col][grp * 4]) =
          make_uint2((unsigned)f2bf(p0[0]) | ((unsigned)f2bf(p0[1]) << 16),
                     (unsigned)f2bf(p0[2]) | ((unsigned)f2bf(p0[3]) << 16));
      *reinterpret_cast<uint2*>(&pl[wv][1][col][16 + grp * 4]) =
          make_uint2((unsigned)f2bf(p1[0]) | ((unsigned)f2bf(p1[1]) << 16),
                     (unsigned)f2bf(p1[2]) | ((unsigned)f2bf(p1[3]) << 16));
      *reinterpret_cast<uint2*>(&pl[wv][1][col][32 + grp * 4]) =
          make_uint2((unsigned)f2bf(p2[0]) | ((unsigned)f2bf(p2[1]) << 16),
                     (unsigned)f2bf(p2[2]) | ((unsigned)f2bf(p2[3]) << 16));
      *reinterpret_cast<uint2*>(&pl[wv][1][col][48 + grp * 4]) =
          make_uint2((unsigned)f2bf(p3[0]) | ((unsigned)f2bf(p3[1]) << 16),
                     (unsigned)f2bf(p3[2]) | ((unsigned)f2bf(p3[3]) << 16));
    }
    const s16x8 pfA0 = *reinterpret_cast<const s16x8*>(&pl[wv][0][col][grp * 8]);
    const s16x8 pfB0 = *reinterpret_cast<const s16x8*>(&pl[wv][0][col][32 + grp * 8]);
    const s16x8 pfA1 = *reinterpret_cast<const s16x8*>(&pl[wv][1][col][grp * 8]);
    const s16x8 pfB1 = *reinterpret_cast<const s16x8*>(&pl[wv][1][col][32 + grp * 8]);
#pragma unroll
    for (int t = 0; t < 8; ++t) {
      const s16x8 vfA = *reinterpret_cast<const s16x8*>(vb + t * 512 + fo);
      const s16x8 vfB = *reinterpret_cast<const s16x8*>(vb + 4096 + t * 512 + fo);
      oa0[t] = __builtin_amdgcn_mfma_f32_16x16x32_bf16(vfA, pfA0, oa0[t], 0, 0, 0);
      oa0[t] = __builtin_amdgcn_mfma_f32_16x16x32_bf16(vfB, pfB0, oa0[t], 0, 0, 0);
      oa1[t] = __builtin_amdgcn_mfma_f32_16x16x32_bf16(vfA, pfA1, oa1[t], 0, 0, 0);
      oa1[t] = __builtin_amdgcn_mfma_f32_16x16x32_bf16(vfB, pfB1, oa1[t], 0, 0, 0);
    }
    __syncthreads();  // drains DMA (vmcnt) + syncs buffer swap
  }
  // ---- epilogue: normalize own O, stage in LDS (reuse kv), project ----
  unsigned short* obw = &kv[0][0] + (size_t)wv * (32 * 136);
  const float ri0 = 1.f / l0, ri1 = 1.f / l1;
#pragma unroll
  for (int t = 0; t < 8; ++t) {
    *reinterpret_cast<uint2*>(obw + col * 136 + t * 16 + grp * 4) =
        make_uint2((unsigned)f2bf(oa0[t][0] * ri0) | ((unsigned)f2bf(oa0[t][1] * ri0) << 16),
                   (unsigned)f2bf(oa0[t][2] * ri0) | ((unsigned)f2bf(oa0[t][3] * ri0) << 16));
    *reinterpret_cast<uint2*>(obw + (16 + col) * 136 + t * 16 + grp * 4) =
        make_uint2((unsigned)f2bf(oa1[t][0] * ri1) | ((unsigned)f2bf(oa1[t][1] * ri1) << 16),
                   (unsigned)f2bf(oa1[t][2] * ri1) | ((unsigned)f2bf(oa1[t][3] * ri1) << 16));
  }
  s16x8 of0[4], of1[4];
#pragma unroll
  for (int ks = 0; ks < 4; ++ks) {
    of0[ks] = *reinterpret_cast<const s16x8*>(obw + col * 136 + ks * 32 + grp * 8);
    of1[ks] = *reinterpret_cast<const s16x8*>(obw + (16 + col) * 136 + ks * 32 + grp * 8);
  }
  const float gamma = gammap[0];
  const float* xb2 = x + (size_t)b * CIN * NN;
  float* outb = out + (size_t)b * CIN * NN;
#pragma unroll 1
  for (int t2 = 0; t2 < 16; ++t2) {
    f32x4 a20 = {0.f, 0.f, 0.f, 0.f};
    f32x4 a21 = {0.f, 0.f, 0.f, 0.f};
#pragma unroll
    for (int ks = 0; ks < 4; ++ks) {
      const s16x8 wf = *reinterpret_cast<const s16x8*>(
          wo2 + (size_t)(t2 * 16 + ks * 4 + grp) * 128 + col * 8);
      a20 = __builtin_amdgcn_mfma_f32_16x16x32_bf16(wf, of0[ks], a20, 0, 0, 0);
      a21 = __builtin_amdgcn_mfma_f32_16x16x32_bf16(wf, of1[ks], a21, 0, 0, 0);
    }
#pragma unroll
    for (int r = 0; r < 4; ++r) {
      const size_t idx = (size_t)(t2 * 16 + grp * 4 + r) * NN + n0 + col;
      outb[idx] = fmaf(gamma, a20[r], xb2[idx]);
      outb[idx + 16] = fmaf(gamma, a21[r], xb2[idx + 16]);
    }
  }
}

extern "C" void kernel_launch(void* const* d_in, const int* in_sizes, int n_in,
                              void* d_out, int out_size, void* d_ws, size_t ws_size,
                              hipStream_t stream) {
  const float* x = (const float*)d_in[0];
  const float* w_theta = (const float*)d_in[1];
  const float* w_phi = (const float*)d_in[2];
  const float* w_g = (const float*)d_in[3];
  const float* w_o = (const float*)d_in[4];
  const float* gamma = (const float*)d_in[5];
  float* out = (float*)d_out;
  char* ws = (char*)d_ws;
  unsigned short* theta = (unsigned short*)(ws + 0);
  unsigned short* phi2 = (unsigned short*)(ws + 4194304);
  unsigned short* g2 = (unsigned short*)(ws + 5242880);
  unsigned short* wo2 = (unsigned short*)(ws + 9437184);
  unsigned short* wcat = (unsigned short*)(ws + 9502720);

  k_wcvt<<<dim3(320), 256, 0, stream>>>(w_theta, w_phi, w_g, w_o, wcat, wo2);
  k_proj<<<dim3(NN / 128, NB), 512, 0, stream>>>(x, wcat, theta, phi2, g2);
  k_attn_out<<<dim3(NN / 128, NB), 256, 0, stream>>>(theta, phi2, g2, wo2, x, gamma, out);
}